// Round 4
// baseline (241.040 us; speedup 1.0000x reference)
//
#include <hip/hip_runtime.h>
#include <hip/hip_bf16.h>

#define BB 4
#define SS 2048
#define DM 1024
#define DN 64

typedef short short8 __attribute__((ext_vector_type(8)));
typedef float f32x4 __attribute__((ext_vector_type(4)));
typedef unsigned short ushort;

__device__ __forceinline__ ushort f2bf(float f) {
    union { float f; unsigned u; } v; v.f = f;
    unsigned r = v.u + 0x7fffu + ((v.u >> 16) & 1u);
    return (ushort)(r >> 16);
}
__device__ __forceinline__ float bf2f(ushort h) {
    union { unsigned u; float f; } v; v.u = ((unsigned)h) << 16; return v.f;
}

// ---------------------------------------------------------------------------
// prep_w: convert w_q|w_k|w_v (each [64][1024] fp32) to bf16, same layout.
// ---------------------------------------------------------------------------
__global__ __launch_bounds__(256) void prep_w(
    const float* __restrict__ wq, const float* __restrict__ wk,
    const float* __restrict__ wv, ushort* __restrict__ w_bf)
{
    int i = blockIdx.x * 256 + threadIdx.x;
    int p = i >> 14;
    int j = (i & 16383) * 4;
    const float* src = (p == 0) ? wq : (p == 1) ? wk : wv;
    float4 f = *(const float4*)(src + j);
    ushort o[4] = { f2bf(f.x), f2bf(f.y), f2bf(f.z), f2bf(f.w) };
    *(unsigned long long*)(w_bf + p * 65536 + j) = *(unsigned long long*)o;
}

// ---------------------------------------------------------------------------
// proj_main: split-K projection GEMM partials. One wave = 16 rows x 64 cols
// x K-slice of DM/PS. 512*PS*3 waves -> 24 waves/CU at PS=4 (latency hiding
// via TLP, not unroll pragmas). fp32 partials [3*PS][8192][64].
// ---------------------------------------------------------------------------
template<int PS>
__global__ __launch_bounds__(256) void proj_main(
    const float* __restrict__ q, const float* __restrict__ k, const float* __restrict__ v,
    const ushort* __restrict__ w_bf, float* __restrict__ part)
{
    const int tid  = threadIdx.x;
    const int wv_id = tid >> 6;
    const int lane  = tid & 63;
    const int l16   = lane & 15;
    const int quad  = lane >> 4;

    const int w    = blockIdx.x * 4 + wv_id;
    const int proj = w / (512 * PS);
    const int rem  = w % (512 * PS);
    const int g    = rem / PS;
    const int slice = rem % PS;
    const int m0   = g * 16;

    const float* x   = (proj == 0) ? q : (proj == 1) ? k : v;
    const ushort* wb = w_bf + proj * 65536;

    const float* arow = x + (size_t)(m0 + l16) * DM + quad * 8;
    const int k_begin = slice * (DM / PS);
    const int k_end   = k_begin + (DM / PS);

    f32x4 acc[4];
#pragma unroll
    for (int t = 0; t < 4; t++) acc[t] = (f32x4){0.f, 0.f, 0.f, 0.f};

#pragma unroll 2
    for (int kb = k_begin; kb < k_end; kb += 32) {
        float4 f0 = *(const float4*)(arow + kb);
        float4 f1 = *(const float4*)(arow + kb + 4);
        ushort ta[8] = { f2bf(f0.x), f2bf(f0.y), f2bf(f0.z), f2bf(f0.w),
                         f2bf(f1.x), f2bf(f1.y), f2bf(f1.z), f2bf(f1.w) };
        short8 a = *(short8*)ta;
#pragma unroll
        for (int t = 0; t < 4; t++) {
            short8 b = *(const short8*)(wb + (size_t)(t * 16 + l16) * DM + kb + quad * 8);
            acc[t] = __builtin_amdgcn_mfma_f32_16x16x32_bf16(a, b, acc[t], 0, 0, 0);
        }
    }

    // store fp32 partials; C/D layout: n = t*16+l16, row = quad*4+r
    float* pb = part + ((size_t)(proj * PS + slice) * (BB * SS) + m0) * DN;
#pragma unroll
    for (int t = 0; t < 4; t++)
#pragma unroll
        for (int r = 0; r < 4; r++)
            pb[(size_t)(quad * 4 + r) * DN + t * 16 + l16] = acc[t][r];
}

// ---------------------------------------------------------------------------
// proj_reduce: sum PS partials + bias -> bf16 qp/kp/vpT (vpT transposed).
// ---------------------------------------------------------------------------
__global__ __launch_bounds__(256) void proj_reduce(
    const float* __restrict__ part,
    const float* __restrict__ bq, const float* __restrict__ bk, const float* __restrict__ bvp,
    ushort* __restrict__ qp, ushort* __restrict__ kp, ushort* __restrict__ vpT, int PS)
{
    const int idx  = blockIdx.x * 256 + threadIdx.x;   // 3*8192*64
    const int proj = idx / (BB * SS * DN);
    const int rem  = idx % (BB * SS * DN);
    const int row  = rem >> 6;
    const int n    = rem & 63;

    const float* bias = (proj == 0) ? bq : (proj == 1) ? bk : bvp;
    float s = bias[n];
    for (int i = 0; i < PS; i++)
        s += part[((size_t)(proj * PS + i) * (BB * SS) + row) * DN + n];
    ushort h = f2bf(s);
    if (proj == 0)      qp[(size_t)row * DN + n] = h;
    else if (proj == 1) kp[(size_t)row * DN + n] = h;
    else {
        int bb = row >> 11, ss = row & 2047;
        vpT[((size_t)bb * DN + n) * SS + ss] = h;
    }
}

// ---------------------------------------------------------------------------
// flash: barrier-free, register double-buffered prefetch of next k-tile's
// mask + kp fragments. One wave = 16 q rows x one key-slice of KPS keys.
// Writes unnormalized bf16 partial O plus fp32 (m, l).
// ---------------------------------------------------------------------------
template<int KPS>
__global__ __launch_bounds__(256, 2) void flash_kernel(
    const float* __restrict__ mask,
    const ushort* __restrict__ qp,
    const ushort* __restrict__ kp,
    const ushort* __restrict__ vpT,
    ushort* __restrict__ part_O,    // [split][8192][64] bf16
    float* __restrict__ part_ml)    // [split][8192][2]
{
    constexpr int NSLICE = SS / KPS;
    constexpr int NIT    = KPS / 64;

    __shared__ __align__(16) ushort p_lds[4][16][72];

    const int tid  = threadIdx.x;
    const int wv   = tid >> 6;
    const int lane = tid & 63;
    const int l16  = lane & 15;
    const int quad = lane >> 4;

    const int gw    = blockIdx.x * 4 + wv;
    const int qg    = gw & 127;
    const int rest  = gw >> 7;
    const int slice = rest % NSLICE;
    const int b     = rest / NSLICE;

    const ushort* qbase = qp + ((size_t)b * SS + qg * 16 + l16) * DN + quad * 8;
    short8 aq0 = *(const short8*)(qbase);
    short8 aq1 = *(const short8*)(qbase + 32);

    float m_r[4] = { -__builtin_inff(), -__builtin_inff(),
                     -__builtin_inff(), -__builtin_inff() };
    float l_r[4] = { 0.f, 0.f, 0.f, 0.f };
    f32x4 Oacc[4];
#pragma unroll
    for (int t = 0; t < 4; t++) Oacc[t] = (f32x4){0.f, 0.f, 0.f, 0.f};

    const size_t mrow0 = ((size_t)b * SS + qg * 16 + quad * 4) * SS;
    const int k_begin = slice * KPS;

    float  mk[2][4][4];
    short8 bk0[2][4], bk1[2][4];

    auto load_tile = [&](int buf, int k0) {
#pragma unroll
        for (int t = 0; t < 4; t++) {
            const ushort* kb_ = kp + ((size_t)b * SS + k0 + t * 16 + l16) * DN + quad * 8;
            bk0[buf][t] = *(const short8*)(kb_);
            bk1[buf][t] = *(const short8*)(kb_ + 32);
        }
#pragma unroll
        for (int t = 0; t < 4; t++)
#pragma unroll
            for (int r = 0; r < 4; r++)
                mk[buf][t][r] = mask[mrow0 + (size_t)r * SS + k0 + t * 16 + l16];
    };

    load_tile(0, k_begin);

#pragma unroll
    for (int it = 0; it < NIT; ++it) {
        const int cur = it & 1;
        const int k0  = k_begin + it * 64;

        if (it + 1 < NIT) load_tile(cur ^ 1, k0 + 64);

        short8 bv0[4], bv1[4];
#pragma unroll
        for (int tf = 0; tf < 4; tf++) {
            const ushort* vb_ = vpT + ((size_t)b * DN + tf * 16 + l16) * SS + k0 + quad * 8;
            bv0[tf] = *(const short8*)(vb_);
            bv1[tf] = *(const short8*)(vb_ + 32);
        }

        f32x4 sc[4];
#pragma unroll
        for (int t = 0; t < 4; t++) {
            f32x4 z = (f32x4){0.f, 0.f, 0.f, 0.f};
            z = __builtin_amdgcn_mfma_f32_16x16x32_bf16(aq0, bk0[cur][t], z, 0, 0, 0);
            z = __builtin_amdgcn_mfma_f32_16x16x32_bf16(aq1, bk1[cur][t], z, 0, 0, 0);
            sc[t] = z;
        }

#pragma unroll
        for (int r = 0; r < 4; r++) {
            float s[4];
            float tmax = -__builtin_inff();
#pragma unroll
            for (int t = 0; t < 4; t++) {
                s[t] = sc[t][r] * 0.125f - 1e9f * mk[cur][t][r];
                tmax = fmaxf(tmax, s[t]);
            }
#pragma unroll
            for (int off = 8; off >= 1; off >>= 1)
                tmax = fmaxf(tmax, __shfl_xor(tmax, off, 16));
            float mnew  = fmaxf(m_r[r], tmax);
            float alpha = __expf(m_r[r] - mnew);
            m_r[r] = mnew;
            float rs = 0.f;
#pragma unroll
            for (int t = 0; t < 4; t++) {
                float pv = __expf(s[t] - mnew);
                rs += pv;
                p_lds[wv][quad * 4 + r][t * 16 + l16] = f2bf(pv);
            }
#pragma unroll
            for (int off = 8; off >= 1; off >>= 1)
                rs += __shfl_xor(rs, off, 16);
            l_r[r] = l_r[r] * alpha + rs;
#pragma unroll
            for (int tf = 0; tf < 4; tf++)
                Oacc[tf][r] *= alpha;
        }

        short8 ap0 = *(const short8*)&p_lds[wv][l16][quad * 8];
        short8 ap1 = *(const short8*)&p_lds[wv][l16][32 + quad * 8];
#pragma unroll
        for (int tf = 0; tf < 4; tf++) {
            Oacc[tf] = __builtin_amdgcn_mfma_f32_16x16x32_bf16(ap0, bv0[tf], Oacc[tf], 0, 0, 0);
            Oacc[tf] = __builtin_amdgcn_mfma_f32_16x16x32_bf16(ap1, bv1[tf], Oacc[tf], 0, 0, 0);
        }
    }

    const int rowg = (b * SS + qg * 16) + quad * 4;
#pragma unroll
    for (int r = 0; r < 4; r++) {
        size_t row = (size_t)rowg + r;
        if (l16 == 0) {
            part_ml[((size_t)slice * (BB * SS) + row) * 2 + 0] = m_r[r];
            part_ml[((size_t)slice * (BB * SS) + row) * 2 + 1] = l_r[r];
        }
#pragma unroll
        for (int tf = 0; tf < 4; tf++)
            part_O[((size_t)slice * (BB * SS) + row) * DN + tf * 16 + l16] =
                f2bf(Oacc[tf][r]);
    }
}

// ---------------------------------------------------------------------------
// combine: merge nslice partials per row; normalize.
// ---------------------------------------------------------------------------
__global__ __launch_bounds__(256) void combine_kernel(
    const ushort* __restrict__ part_O, const float* __restrict__ part_ml,
    float* __restrict__ out, int nslice)
{
    const int tid = threadIdx.x;
    const int row = blockIdx.x * 4 + (tid >> 6);
    const int f   = tid & 63;

    float ms[8], ls[8];
    float M = -__builtin_inff();
    for (int i = 0; i < nslice; i++) {
        ms[i] = part_ml[((size_t)i * (BB * SS) + row) * 2 + 0];
        ls[i] = part_ml[((size_t)i * (BB * SS) + row) * 2 + 1];
        M = fmaxf(M, ms[i]);
    }
    float L = 0.f, acc = 0.f;
    for (int i = 0; i < nslice; i++) {
        float e = __expf(ms[i] - M);
        L += e * ls[i];
        acc += e * bf2f(part_O[((size_t)i * (BB * SS) + row) * DN + f]);
    }
    out[(size_t)row * DN + f] = acc / L;
}

extern "C" void kernel_launch(void* const* d_in, const int* in_sizes, int n_in,
                              void* d_out, int out_size, void* d_ws, size_t ws_size,
                              hipStream_t stream) {
    const float* q    = (const float*)d_in[0];
    const float* k    = (const float*)d_in[1];
    const float* v    = (const float*)d_in[2];
    const float* mask = (const float*)d_in[3];
    const float* wq   = (const float*)d_in[4];
    const float* bq   = (const float*)d_in[5];
    const float* wk   = (const float*)d_in[6];
    const float* bk   = (const float*)d_in[7];
    const float* wv   = (const float*)d_in[8];
    const float* bv   = (const float*)d_in[9];
    float* out = (float*)d_out;

    // fixed workspace
    char* p = (char*)d_ws;
    ushort* w_bf = (ushort*)p;   p += 3 * 65536 * sizeof(ushort);   // 384 KB
    ushort* qp   = (ushort*)p;   p += (size_t)BB * SS * DN * 2;     // 1 MB
    ushort* kp   = (ushort*)p;   p += (size_t)BB * SS * DN * 2;     // 1 MB
    ushort* vpT  = (ushort*)p;   p += (size_t)BB * SS * DN * 2;     // 1 MB
    size_t fixed = (size_t)(p - (char*)d_ws);

    // flash split (partials: ml fp32 + O bf16)
    int split = 8;
    size_t flash_bytes;
    for (;;) {
        flash_bytes = (size_t)split * BB * SS * 2 * 4 + (size_t)split * BB * SS * DN * 2;
        if (split == 1 || fixed + flash_bytes <= ws_size) break;
        split >>= 1;
    }

    // proj split-K (fp32 partials), aliased over the flash-partial region
    // (proj_main/proj_reduce complete before flash writes — stream-ordered)
    int PS = 4;
    while (PS > 1) {
        size_t proj_bytes = (size_t)3 * PS * BB * SS * DN * 4;
        size_t need = proj_bytes > flash_bytes ? proj_bytes : flash_bytes;
        if (fixed + need <= ws_size) break;
        PS >>= 1;
    }

    float*  proj_part = (float*)p;
    float*  part_ml   = (float*)p;   p += (size_t)split * BB * SS * 2 * 4;
    ushort* part_O    = (ushort*)p;

    prep_w<<<192, 256, 0, stream>>>(wq, wk, wv, w_bf);
    switch (PS) {
        case 4: proj_main<4><<<128 * 3 * 4, 256, 0, stream>>>(q, k, v, w_bf, proj_part); break;
        case 2: proj_main<2><<<128 * 3 * 2, 256, 0, stream>>>(q, k, v, w_bf, proj_part); break;
        default: proj_main<1><<<128 * 3, 256, 0, stream>>>(q, k, v, w_bf, proj_part); break;
    }
    proj_reduce<<<(3 * BB * SS * DN) / 256, 256, 0, stream>>>(proj_part, bq, bk, bv,
                                                              qp, kp, vpT, PS);
    switch (split) {
        case 8:  flash_kernel<256> <<<128 * 8, 256, 0, stream>>>(mask, qp, kp, vpT, part_O, part_ml); break;
        case 4:  flash_kernel<512> <<<128 * 4, 256, 0, stream>>>(mask, qp, kp, vpT, part_O, part_ml); break;
        case 2:  flash_kernel<1024><<<128 * 2, 256, 0, stream>>>(mask, qp, kp, vpT, part_O, part_ml); break;
        default: flash_kernel<2048><<<128 * 1, 256, 0, stream>>>(mask, qp, kp, vpT, part_O, part_ml); break;
    }
    combine_kernel<<<(BB * SS) / 4, 256, 0, stream>>>(part_O, part_ml, out, split);
}

// Round 5
// 226.865 us; speedup vs baseline: 1.0625x; 1.0625x over previous
//
#include <hip/hip_runtime.h>
#include <hip/hip_bf16.h>

#define BB 4
#define SS 2048
#define DM 1024
#define DN 64

typedef short short8 __attribute__((ext_vector_type(8)));
typedef float f32x4 __attribute__((ext_vector_type(4)));
typedef unsigned short ushort;

__device__ __forceinline__ ushort f2bf(float f) {
    union { float f; unsigned u; } v; v.f = f;
    unsigned r = v.u + 0x7fffu + ((v.u >> 16) & 1u);
    return (ushort)(r >> 16);
}
__device__ __forceinline__ float bf2f(ushort h) {
    union { unsigned u; float f; } v; v.u = ((unsigned)h) << 16; return v.f;
}

// ---------------------------------------------------------------------------
// prep_w: convert w_q|w_k|w_v (each [64][1024] fp32) to bf16, same layout.
// ---------------------------------------------------------------------------
__global__ __launch_bounds__(256) void prep_w(
    const float* __restrict__ wq, const float* __restrict__ wk,
    const float* __restrict__ wv, ushort* __restrict__ w_bf)
{
    int i = blockIdx.x * 256 + threadIdx.x;
    int p = i >> 14;
    int j = (i & 16383) * 4;
    const float* src = (p == 0) ? wq : (p == 1) ? wk : wv;
    float4 f = *(const float4*)(src + j);
    ushort o[4] = { f2bf(f.x), f2bf(f.y), f2bf(f.z), f2bf(f.w) };
    *(unsigned long long*)(w_bf + p * 65536 + j) = *(unsigned long long*)o;
}

// ---------------------------------------------------------------------------
// proj: tiled GEMM with COALESCED staging. Block = 32 rows x 64 cols, 256 thr.
// K-loop BK=128, double-buffered LDS bf16 A-tile, one barrier/step, next
// step's (contiguous 512B-segment) global loads issued before the barrier.
// Waves: rg = wv&1 (16-row group), nh = wv>>1 (32-col half). B-frags direct
// from L2-hot bf16 w. qp/kp row-major bf16; vp transposed [4][64][2048].
// ---------------------------------------------------------------------------
__global__ __launch_bounds__(256) void proj_kernel(
    const float* __restrict__ q, const float* __restrict__ k, const float* __restrict__ v,
    const ushort* __restrict__ w_bf,
    const float* __restrict__ bq, const float* __restrict__ bk, const float* __restrict__ bvp,
    ushort* __restrict__ qp, ushort* __restrict__ kp, ushort* __restrict__ vpT)
{
    __shared__ __align__(16) ushort A_lds[2][32][136];   // 17.4 KB; stride 272B -> 2-way alias only

    const int tid  = threadIdx.x;
    const int proj = blockIdx.y;
    const int m0   = blockIdx.x * 32;

    const float* x    = (proj == 0) ? q  : (proj == 1) ? k  : v;
    const ushort* wb  = w_bf + proj * 65536;
    const float* bias = (proj == 0) ? bq : (proj == 1) ? bk : bvp;

    const int wv   = tid >> 6;
    const int lane = tid & 63;
    const int l16  = lane & 15;
    const int quad = lane >> 4;
    const int rg   = wv & 1;     // row group (16 rows)
    const int nh   = wv >> 1;    // n half (32 cols)

    // staging map: idx = r*256+tid -> row = idx>>5, lc = idx&31 (512B contiguous per row)
    const int srow = tid >> 5;         // base row for r=0 (rows 0..7)
    const int slc  = tid & 31;

    float4 pf[4];
    auto issue_loads = [&](int kb) {
#pragma unroll
        for (int r = 0; r < 4; r++)
            pf[r] = *(const float4*)&x[(size_t)(m0 + srow + r * 8) * DM + kb + slc * 4];
    };
    auto write_stage = [&](int buf) {
#pragma unroll
        for (int r = 0; r < 4; r++) {
            ushort t4[4] = { f2bf(pf[r].x), f2bf(pf[r].y), f2bf(pf[r].z), f2bf(pf[r].w) };
            *(unsigned long long*)&A_lds[buf][srow + r * 8][slc * 4] =
                *(unsigned long long*)t4;
        }
    };

    f32x4 acc[2];
    acc[0] = (f32x4){0.f, 0.f, 0.f, 0.f};
    acc[1] = (f32x4){0.f, 0.f, 0.f, 0.f};

    issue_loads(0);

#pragma unroll
    for (int s = 0; s < 8; s++) {
        const int buf = s & 1;
        write_stage(buf);                      // consume pf of step s
        if (s < 7) issue_loads((s + 1) * 128); // next step's loads in flight across barrier+compute
        __syncthreads();                       // (a) A_lds[buf] visible; (b) buf^1 reads done

        const int kb = s * 128;
#pragma unroll
        for (int kk = 0; kk < 128; kk += 32) {
            short8 a = *(const short8*)&A_lds[buf][rg * 16 + l16][kk + quad * 8];
#pragma unroll
            for (int tt = 0; tt < 2; tt++) {
                const int t = nh * 2 + tt;
                short8 b = *(const short8*)(wb + (size_t)(t * 16 + l16) * DM + kb + kk + quad * 8);
                acc[tt] = __builtin_amdgcn_mfma_f32_16x16x32_bf16(a, b, acc[tt], 0, 0, 0);
            }
        }
    }

    // epilogue: C/D layout col = t*16+l16, row = quad*4+r
#pragma unroll
    for (int tt = 0; tt < 2; tt++) {
        const int n = (nh * 2 + tt) * 16 + l16;
        float bb_ = bias[n];
#pragma unroll
        for (int r = 0; r < 4; r++) {
            int grow = m0 + rg * 16 + quad * 4 + r;
            ushort h = f2bf(acc[tt][r] + bb_);
            if (proj == 0)      qp[(size_t)grow * DN + n] = h;
            else if (proj == 1) kp[(size_t)grow * DN + n] = h;
            else {
                int bb = grow >> 11, ss = grow & 2047;
                vpT[((size_t)bb * DN + n) * SS + ss] = h;
            }
        }
    }
}

// ---------------------------------------------------------------------------
// flash: barrier-free, register double-buffered prefetch of next k-tile's
// mask + kp fragments. One wave = 16 q rows x one key-slice of KPS keys.
// Writes unnormalized bf16 partial O plus fp32 (m, l).
// ---------------------------------------------------------------------------
template<int KPS>
__global__ __launch_bounds__(256, 2) void flash_kernel(
    const float* __restrict__ mask,
    const ushort* __restrict__ qp,
    const ushort* __restrict__ kp,
    const ushort* __restrict__ vpT,
    ushort* __restrict__ part_O,    // [split][8192][64] bf16
    float* __restrict__ part_ml)    // [split][8192][2]
{
    constexpr int NSLICE = SS / KPS;
    constexpr int NIT    = KPS / 64;

    __shared__ __align__(16) ushort p_lds[4][16][72];

    const int tid  = threadIdx.x;
    const int wv   = tid >> 6;
    const int lane = tid & 63;
    const int l16  = lane & 15;
    const int quad = lane >> 4;

    const int gw    = blockIdx.x * 4 + wv;
    const int qg    = gw & 127;
    const int rest  = gw >> 7;
    const int slice = rest % NSLICE;
    const int b     = rest / NSLICE;

    const ushort* qbase = qp + ((size_t)b * SS + qg * 16 + l16) * DN + quad * 8;
    short8 aq0 = *(const short8*)(qbase);
    short8 aq1 = *(const short8*)(qbase + 32);

    float m_r[4] = { -__builtin_inff(), -__builtin_inff(),
                     -__builtin_inff(), -__builtin_inff() };
    float l_r[4] = { 0.f, 0.f, 0.f, 0.f };
    f32x4 Oacc[4];
#pragma unroll
    for (int t = 0; t < 4; t++) Oacc[t] = (f32x4){0.f, 0.f, 0.f, 0.f};

    const size_t mrow0 = ((size_t)b * SS + qg * 16 + quad * 4) * SS;
    const int k_begin = slice * KPS;

    float  mk[2][4][4];
    short8 bk0[2][4], bk1[2][4];

    auto load_tile = [&](int buf, int k0) {
#pragma unroll
        for (int t = 0; t < 4; t++) {
            const ushort* kb_ = kp + ((size_t)b * SS + k0 + t * 16 + l16) * DN + quad * 8;
            bk0[buf][t] = *(const short8*)(kb_);
            bk1[buf][t] = *(const short8*)(kb_ + 32);
        }
#pragma unroll
        for (int t = 0; t < 4; t++)
#pragma unroll
            for (int r = 0; r < 4; r++)
                mk[buf][t][r] = mask[mrow0 + (size_t)r * SS + k0 + t * 16 + l16];
    };

    load_tile(0, k_begin);

#pragma unroll
    for (int it = 0; it < NIT; ++it) {
        const int cur = it & 1;
        const int k0  = k_begin + it * 64;

        if (it + 1 < NIT) load_tile(cur ^ 1, k0 + 64);

        short8 bv0[4], bv1[4];
#pragma unroll
        for (int tf = 0; tf < 4; tf++) {
            const ushort* vb_ = vpT + ((size_t)b * DN + tf * 16 + l16) * SS + k0 + quad * 8;
            bv0[tf] = *(const short8*)(vb_);
            bv1[tf] = *(const short8*)(vb_ + 32);
        }

        f32x4 sc[4];
#pragma unroll
        for (int t = 0; t < 4; t++) {
            f32x4 z = (f32x4){0.f, 0.f, 0.f, 0.f};
            z = __builtin_amdgcn_mfma_f32_16x16x32_bf16(aq0, bk0[cur][t], z, 0, 0, 0);
            z = __builtin_amdgcn_mfma_f32_16x16x32_bf16(aq1, bk1[cur][t], z, 0, 0, 0);
            sc[t] = z;
        }

#pragma unroll
        for (int r = 0; r < 4; r++) {
            float s[4];
            float tmax = -__builtin_inff();
#pragma unroll
            for (int t = 0; t < 4; t++) {
                s[t] = sc[t][r] * 0.125f - 1e9f * mk[cur][t][r];
                tmax = fmaxf(tmax, s[t]);
            }
#pragma unroll
            for (int off = 8; off >= 1; off >>= 1)
                tmax = fmaxf(tmax, __shfl_xor(tmax, off, 16));
            float mnew  = fmaxf(m_r[r], tmax);
            float alpha = __expf(m_r[r] - mnew);
            m_r[r] = mnew;
            float rs = 0.f;
#pragma unroll
            for (int t = 0; t < 4; t++) {
                float pv = __expf(s[t] - mnew);
                rs += pv;
                p_lds[wv][quad * 4 + r][t * 16 + l16] = f2bf(pv);
            }
#pragma unroll
            for (int off = 8; off >= 1; off >>= 1)
                rs += __shfl_xor(rs, off, 16);
            l_r[r] = l_r[r] * alpha + rs;
#pragma unroll
            for (int tf = 0; tf < 4; tf++)
                Oacc[tf][r] *= alpha;
        }

        short8 ap0 = *(const short8*)&p_lds[wv][l16][quad * 8];
        short8 ap1 = *(const short8*)&p_lds[wv][l16][32 + quad * 8];
#pragma unroll
        for (int tf = 0; tf < 4; tf++) {
            Oacc[tf] = __builtin_amdgcn_mfma_f32_16x16x32_bf16(ap0, bv0[tf], Oacc[tf], 0, 0, 0);
            Oacc[tf] = __builtin_amdgcn_mfma_f32_16x16x32_bf16(ap1, bv1[tf], Oacc[tf], 0, 0, 0);
        }
    }

    const int rowg = (b * SS + qg * 16) + quad * 4;
#pragma unroll
    for (int r = 0; r < 4; r++) {
        size_t row = (size_t)rowg + r;
        if (l16 == 0) {
            part_ml[((size_t)slice * (BB * SS) + row) * 2 + 0] = m_r[r];
            part_ml[((size_t)slice * (BB * SS) + row) * 2 + 1] = l_r[r];
        }
#pragma unroll
        for (int tf = 0; tf < 4; tf++)
            part_O[((size_t)slice * (BB * SS) + row) * DN + tf * 16 + l16] =
                f2bf(Oacc[tf][r]);
    }
}

// ---------------------------------------------------------------------------
// combine: merge nslice partials per row; normalize.
// ---------------------------------------------------------------------------
__global__ __launch_bounds__(256) void combine_kernel(
    const ushort* __restrict__ part_O, const float* __restrict__ part_ml,
    float* __restrict__ out, int nslice)
{
    const int tid = threadIdx.x;
    const int row = blockIdx.x * 4 + (tid >> 6);
    const int f   = tid & 63;

    float ms[8], ls[8];
    float M = -__builtin_inff();
    for (int i = 0; i < nslice; i++) {
        ms[i] = part_ml[((size_t)i * (BB * SS) + row) * 2 + 0];
        ls[i] = part_ml[((size_t)i * (BB * SS) + row) * 2 + 1];
        M = fmaxf(M, ms[i]);
    }
    float L = 0.f, acc = 0.f;
    for (int i = 0; i < nslice; i++) {
        float e = __expf(ms[i] - M);
        L += e * ls[i];
        acc += e * bf2f(part_O[((size_t)i * (BB * SS) + row) * DN + f]);
    }
    out[(size_t)row * DN + f] = acc / L;
}

extern "C" void kernel_launch(void* const* d_in, const int* in_sizes, int n_in,
                              void* d_out, int out_size, void* d_ws, size_t ws_size,
                              hipStream_t stream) {
    const float* q    = (const float*)d_in[0];
    const float* k    = (const float*)d_in[1];
    const float* v    = (const float*)d_in[2];
    const float* mask = (const float*)d_in[3];
    const float* wq   = (const float*)d_in[4];
    const float* bq   = (const float*)d_in[5];
    const float* wk   = (const float*)d_in[6];
    const float* bk   = (const float*)d_in[7];
    const float* wv   = (const float*)d_in[8];
    const float* bv   = (const float*)d_in[9];
    float* out = (float*)d_out;

    // workspace
    char* p = (char*)d_ws;
    ushort* w_bf = (ushort*)p;   p += 3 * 65536 * sizeof(ushort);   // 384 KB
    ushort* qp   = (ushort*)p;   p += (size_t)BB * SS * DN * 2;     // 1 MB
    ushort* kp   = (ushort*)p;   p += (size_t)BB * SS * DN * 2;     // 1 MB
    ushort* vpT  = (ushort*)p;   p += (size_t)BB * SS * DN * 2;     // 1 MB
    size_t fixed = (size_t)(p - (char*)d_ws);

    int split = 8;
    for (;;) {
        size_t flash_bytes = (size_t)split * BB * SS * 2 * 4 + (size_t)split * BB * SS * DN * 2;
        if (split == 1 || fixed + flash_bytes <= ws_size) break;
        split >>= 1;
    }

    float*  part_ml = (float*)p;   p += (size_t)split * BB * SS * 2 * 4;
    ushort* part_O  = (ushort*)p;

    prep_w<<<192, 256, 0, stream>>>(wq, wk, wv, w_bf);
    proj_kernel<<<dim3(256, 3), 256, 0, stream>>>(q, k, v, w_bf, bq, bk, bv, qp, kp, vpT);
    switch (split) {
        case 8:  flash_kernel<256> <<<128 * 8, 256, 0, stream>>>(mask, qp, kp, vpT, part_O, part_ml); break;
        case 4:  flash_kernel<512> <<<128 * 4, 256, 0, stream>>>(mask, qp, kp, vpT, part_O, part_ml); break;
        case 2:  flash_kernel<1024><<<128 * 2, 256, 0, stream>>>(mask, qp, kp, vpT, part_O, part_ml); break;
        default: flash_kernel<2048><<<128 * 1, 256, 0, stream>>>(mask, qp, kp, vpT, part_O, part_ml); break;
    }
    combine_kernel<<<(BB * SS) / 4, 256, 0, stream>>>(part_O, part_ml, out, split);
}